// Round 1
// baseline (3044.865 us; speedup 1.0000x reference)
//
#include <hip/hip_runtime.h>
#include <cmath>

// ---------------------------------------------------------------------------
// StackAttCore: 3x LSTM cell + 2x additive attention, B=256 L=196 R=1024 A=512 E=1024
// Round 1: correct fp32 baseline. GEMMs = simple 64x64x16 LDS-tiled fp32.
// ---------------------------------------------------------------------------

#define B_ 256
#define L_ 196
#define R_ 1024
#define A_ 512
#define E_ 1024

// C[M,N] (+)= X[M,K] @ W[N,K]^T   (row-major, all dims multiples of 64/16)
__global__ __launch_bounds__(256) void gemm64(
    float* __restrict__ C, int ldc,
    const float* __restrict__ X, int ldx,
    const float* __restrict__ W, int ldw,
    int K, int acc)
{
  __shared__ float As[64 * 16];   // [m][k]
  __shared__ float Bs[64 * 16];   // [n][k]
  const int tid = threadIdx.x;
  const int n0 = blockIdx.x * 64;
  const int m0 = blockIdx.y * 64;
  const int row = tid >> 2;          // 0..63
  const int kq  = (tid & 3) * 4;     // 0,4,8,12
  const int tn = tid & 15;
  const int tm = tid >> 4;
  float accv[4][4];
#pragma unroll
  for (int i = 0; i < 4; i++)
#pragma unroll
    for (int j = 0; j < 4; j++) accv[i][j] = 0.f;

  for (int kk = 0; kk < K; kk += 16) {
    float4 xa = *(const float4*)(X + (size_t)(m0 + row) * ldx + kk + kq);
    float4 wb = *(const float4*)(W + (size_t)(n0 + row) * ldw + kk + kq);
    *(float4*)(As + row * 16 + kq) = xa;
    *(float4*)(Bs + row * 16 + kq) = wb;
    __syncthreads();
#pragma unroll
    for (int k = 0; k < 16; k++) {
      float a[4], b[4];
#pragma unroll
      for (int i = 0; i < 4; i++) a[i] = As[(tm * 4 + i) * 16 + k];
#pragma unroll
      for (int j = 0; j < 4; j++) b[j] = Bs[(tn * 4 + j) * 16 + k];
#pragma unroll
      for (int i = 0; i < 4; i++)
#pragma unroll
        for (int j = 0; j < 4; j++) accv[i][j] = fmaf(a[i], b[j], accv[i][j]);
    }
    __syncthreads();
  }
#pragma unroll
  for (int i = 0; i < 4; i++) {
    float4 v = make_float4(accv[i][0], accv[i][1], accv[i][2], accv[i][3]);
    float* cp = C + (size_t)(m0 + tm * 4 + i) * ldc + n0 + tn * 4;
    if (acc) {
      float4 o = *(const float4*)cp;
      v.x += o.x; v.y += o.y; v.z += o.z; v.w += o.w;
    }
    *(float4*)cp = v;
  }
}

// S[256,5120] + biases -> gates -> h,c
__global__ __launch_bounds__(256) void lstm_gates(
    const float* __restrict__ S,
    const float* __restrict__ bi, const float* __restrict__ bh,
    const float* __restrict__ c_prev,
    float* __restrict__ h_out, float* __restrict__ c_out,
    float* __restrict__ h_out2)
{
  int idx = blockIdx.x * 256 + threadIdx.x;   // 0..262143
  int b = idx >> 10;
  int r = idx & 1023;
  const float* s = S + (size_t)b * (5 * R_);
  float s0 = s[r]          + bi[r]          + bh[r];
  float s1 = s[R_ + r]     + bi[R_ + r]     + bh[R_ + r];
  float s2 = s[2*R_ + r]   + bi[2*R_ + r]   + bh[2*R_ + r];
  float s3 = s[3*R_ + r]   + bi[3*R_ + r]   + bh[3*R_ + r];
  float s4 = s[4*R_ + r]   + bi[4*R_ + r]   + bh[4*R_ + r];
  float ig = 1.f / (1.f + expf(-s0));
  float fg = 1.f / (1.f + expf(-s1));
  float og = 1.f / (1.f + expf(-s2));
  float it = fmaxf(s3, s4);
  float c  = fg * c_prev[idx] + ig * it;
  float h  = og * tanhf(c);
  h_out[idx] = h;
  c_out[idx] = c;
  if (h_out2) h_out2[idx] = h;
}

// scores[b,l] = sum_a tanh(p[b,l,a] + attH[b,a] + hb[a]) * aw[a] + ab
// one wave per (b,l), 4 waves/block
__global__ __launch_bounds__(256) void att_scores(
    float* __restrict__ scores,
    const float* __restrict__ p_att,
    const float* __restrict__ attH,
    const float* __restrict__ hb,
    const float* __restrict__ aw,
    const float* __restrict__ ab)
{
  int wid = blockIdx.x * 4 + (threadIdx.x >> 6);
  if (wid >= B_ * L_) return;
  int lane = threadIdx.x & 63;
  int b = wid / L_;
  int l = wid % L_;
  const float* p = p_att + ((size_t)b * L_ + l) * A_;
  const float* q = attH + (size_t)b * A_;
  float part = 0.f;
  float4 p0 = *(const float4*)(p + lane * 8);
  float4 p1 = *(const float4*)(p + lane * 8 + 4);
  float4 q0 = *(const float4*)(q + lane * 8);
  float4 q1 = *(const float4*)(q + lane * 8 + 4);
  float4 h0 = *(const float4*)(hb + lane * 8);
  float4 h1 = *(const float4*)(hb + lane * 8 + 4);
  float4 w0 = *(const float4*)(aw + lane * 8);
  float4 w1 = *(const float4*)(aw + lane * 8 + 4);
  part += tanhf(p0.x + q0.x + h0.x) * w0.x;
  part += tanhf(p0.y + q0.y + h0.y) * w0.y;
  part += tanhf(p0.z + q0.z + h0.z) * w0.z;
  part += tanhf(p0.w + q0.w + h0.w) * w0.w;
  part += tanhf(p1.x + q1.x + h1.x) * w1.x;
  part += tanhf(p1.y + q1.y + h1.y) * w1.y;
  part += tanhf(p1.z + q1.z + h1.z) * w1.z;
  part += tanhf(p1.w + q1.w + h1.w) * w1.w;
#pragma unroll
  for (int off = 32; off > 0; off >>= 1) part += __shfl_down(part, off);
  if (lane == 0) scores[wid] = part + ab[0];
}

// per-b softmax over L=196, in place
__global__ __launch_bounds__(256) void att_softmax(float* __restrict__ sc)
{
  int b = blockIdx.x;
  int t = threadIdx.x;
  __shared__ float buf[256];
  float v = (t < L_) ? sc[b * L_ + t] : -1e30f;
  buf[t] = v;
  __syncthreads();
  for (int s = 128; s > 0; s >>= 1) {
    if (t < s) buf[t] = fmaxf(buf[t], buf[t + s]);
    __syncthreads();
  }
  float m = buf[0];
  __syncthreads();
  float e = (t < L_) ? expf(v - m) : 0.f;
  buf[t] = e;
  __syncthreads();
  for (int s = 128; s > 0; s >>= 1) {
    if (t < s) buf[t] += buf[t + s];
    __syncthreads();
  }
  float inv = 1.f / buf[0];
  if (t < L_) sc[b * L_ + t] = e * inv;
}

// out[b,d] = sum_l w[b,l] * feats[b,l,d]; block = (b, 256-wide d-chunk)
__global__ __launch_bounds__(256) void att_weighted(
    float* __restrict__ out,
    const float* __restrict__ w,
    const float* __restrict__ feats)
{
  int b = blockIdx.x >> 2;
  int dc = blockIdx.x & 3;
  int d = dc * 256 + threadIdx.x;
  const float* f = feats + (size_t)b * L_ * R_ + d;
  const float* wr = w + b * L_;
  float acc = 0.f;
  for (int l = 0; l < L_; l++) acc = fmaf(wr[l], f[(size_t)l * R_], acc);
  out[(size_t)b * R_ + d] = acc;
}

// q2 += h1 + emb2_b
__global__ __launch_bounds__(256) void add_h_bias(
    float* __restrict__ q2, const float* __restrict__ h1,
    const float* __restrict__ eb)
{
  int idx = blockIdx.x * 256 + threadIdx.x;
  q2[idx] += h1[idx] + eb[idx & (R_ - 1)];
}

extern "C" void kernel_launch(void* const* d_in, const int* in_sizes, int n_in,
                              void* d_out, int out_size, void* d_ws, size_t ws_size,
                              hipStream_t stream)
{
  const float* xt        = (const float*)d_in[0];
  const float* fc        = (const float*)d_in[1];
  const float* att_feats = (const float*)d_in[2];
  const float* p_att     = (const float*)d_in[3];
  const float* st_h      = (const float*)d_in[4];
  const float* st_c      = (const float*)d_in[5];
  const float* wi[3] = {(const float*)d_in[6],  (const float*)d_in[10], (const float*)d_in[14]};
  const float* bi[3] = {(const float*)d_in[7],  (const float*)d_in[11], (const float*)d_in[15]};
  const float* wh[3] = {(const float*)d_in[8],  (const float*)d_in[12], (const float*)d_in[16]};
  const float* bh[3] = {(const float*)d_in[9],  (const float*)d_in[13], (const float*)d_in[17]};
  const float* a_hw[2] = {(const float*)d_in[18], (const float*)d_in[22]};
  const float* a_hb[2] = {(const float*)d_in[19], (const float*)d_in[23]};
  const float* a_aw[2] = {(const float*)d_in[20], (const float*)d_in[24]};
  const float* a_ab[2] = {(const float*)d_in[21], (const float*)d_in[25]};
  const float* emb2_w = (const float*)d_in[26];
  const float* emb2_b = (const float*)d_in[27];

  float* out   = (float*)d_out;
  float* out_h2 = out;                         // [256,1024]
  float* out_h  = out + 262144;                // [3,256,1024]
  float* out_c  = out + 262144 + 786432;       // [3,256,1024]

  float* ws  = (float*)d_ws;
  float* S    = ws;                    // 256*5120
  float* attH = S + 1310720;           // 256*512
  float* sc   = attH + 131072;         // 256*196
  float* ar1  = sc + 50176;            // 256*1024
  float* ar2  = ar1 + 262144;
  float* q2   = ar2 + 262144;

  const int BR = B_ * R_;  // 262144
  dim3 blk(256);
  auto gemm = [&](float* C, int ldc, const float* X, int ldx,
                  const float* W, int ldw, int M, int N, int K, int acc) {
    dim3 grid(N / 64, M / 64);
    hipLaunchKernelGGL(gemm64, grid, blk, 0, stream, C, ldc, X, ldx, W, ldw, K, acc);
  };

  // ---------------- LSTM 0: x = [xt, fc], h = st_h[0]
  gemm(S, 5120, xt,       1024, wi[0],        2048, 256, 5120, 1024, 0);
  gemm(S, 5120, fc,       1024, wi[0] + 1024, 2048, 256, 5120, 1024, 1);
  gemm(S, 5120, st_h,     1024, wh[0],        1024, 256, 5120, 1024, 1);
  lstm_gates<<<1024, 256, 0, stream>>>(S, bi[0], bh[0], st_c, out_h, out_c, nullptr);
  const float* h0 = out_h;

  // ---------------- Attention 1 (query = h0)
  gemm(attH, 512, h0, 1024, a_hw[0], 1024, 256, 512, 1024, 0);
  att_scores<<<(B_ * L_) / 4, 256, 0, stream>>>(sc, p_att, attH, a_hb[0], a_aw[0], a_ab[0]);
  att_softmax<<<B_, 256, 0, stream>>>(sc);
  att_weighted<<<B_ * 4, 256, 0, stream>>>(ar1, sc, att_feats);

  // ---------------- LSTM 1: x = [h0, ar1], h = st_h[1]
  gemm(S, 5120, h0,          1024, wi[1],        2048, 256, 5120, 1024, 0);
  gemm(S, 5120, ar1,         1024, wi[1] + 1024, 2048, 256, 5120, 1024, 1);
  gemm(S, 5120, st_h + BR,   1024, wh[1],        1024, 256, 5120, 1024, 1);
  lstm_gates<<<1024, 256, 0, stream>>>(S, bi[1], bh[1], st_c + BR, out_h + BR, out_c + BR, nullptr);
  const float* h1 = out_h + BR;

  // ---------------- q2 = h1 + ar1 @ emb2_w^T + emb2_b
  gemm(q2, 1024, ar1, 1024, emb2_w, 1024, 256, 1024, 1024, 0);
  add_h_bias<<<1024, 256, 0, stream>>>(q2, h1, emb2_b);

  // ---------------- Attention 2 (query = q2)
  gemm(attH, 512, q2, 1024, a_hw[1], 1024, 256, 512, 1024, 0);
  att_scores<<<(B_ * L_) / 4, 256, 0, stream>>>(sc, p_att, attH, a_hb[1], a_aw[1], a_ab[1]);
  att_softmax<<<B_, 256, 0, stream>>>(sc);
  att_weighted<<<B_ * 4, 256, 0, stream>>>(ar2, sc, att_feats);

  // ---------------- LSTM 2: x = [h1, ar2], h = st_h[2]
  gemm(S, 5120, h1,            1024, wi[2],        2048, 256, 5120, 1024, 0);
  gemm(S, 5120, ar2,           1024, wi[2] + 1024, 2048, 256, 5120, 1024, 1);
  gemm(S, 5120, st_h + 2*BR,   1024, wh[2],        1024, 256, 5120, 1024, 1);
  lstm_gates<<<1024, 256, 0, stream>>>(S, bi[2], bh[2], st_c + 2*BR,
                                       out_h + 2*BR, out_c + 2*BR, out_h2);
}

// Round 2
// 345.714 us; speedup vs baseline: 8.8075x; 8.8075x over previous
//
#include <hip/hip_runtime.h>
#include <hip/hip_bf16.h>
#include <cmath>

// ---------------------------------------------------------------------------
// StackAttCore: 3x LSTM + 2x additive attention. B=256 L=196 R=1024 A=512 E=1024
// Round 2: bf16 MFMA GEMMs (fused K=3072 per LSTM), fp32 elementwise/attention.
// ---------------------------------------------------------------------------

#define B_ 256
#define L_ 196
#define R_ 1024
#define A_ 512
#define E_ 1024

typedef __attribute__((ext_vector_type(8))) short bf16x8;
typedef __attribute__((ext_vector_type(4))) float f32x4;

__device__ inline ushort f2bf(float f) {
  __hip_bfloat16 h = __float2bfloat16(f);
  return *(ushort*)&h;
}
__device__ inline uint pk2bf(float lo, float hi) {
  float2 t; t.x = lo; t.y = hi;
  __hip_bfloat162 h = __float22bfloat162_rn(t);
  return *(uint*)&h;
}

// ---------------------------------------------------------------------------
// C[M,N] = Xb(bf16)[M,K] @ [W1|W2](fp32, cvt->bf16)[N,K]^T
// Tile 64x64, BK=64, 4 waves (2x2), each wave 32x32 via 16x16x32 MFMA.
// LDS XOR-swizzled (slot ^= row&7) so frag ds_read_b128 is conflict-free.
// ---------------------------------------------------------------------------
__global__ __launch_bounds__(256) void gemm_mfma(
    float* __restrict__ C, int ldc,
    const ushort* __restrict__ Xb, int ldx,
    const float* __restrict__ W1, int ldw1, int K1,
    const float* __restrict__ W2, int ldw2,
    int K)
{
  __shared__ ushort lA[2][64 * 64];
  __shared__ ushort lB[2][64 * 64];
  const int tid = threadIdx.x;
  const int n0 = blockIdx.x * 64;
  const int m0 = blockIdx.y * 64;

  // staging: thread -> (row 0..63, k-quarter 0..3) ; 16 elems (2 slots of 8)
  const int srow = tid >> 2;
  const int sq = tid & 3;
  const int wz0 = srow * 64 + (((sq * 2) ^ (srow & 7)) * 8);
  const int wz1 = srow * 64 + (((sq * 2 + 1) ^ (srow & 7)) * 8);

  // fragment read offsets
  const int lane = tid & 63;
  const int wid = tid >> 6;
  const int wr = wid >> 1, wc = wid & 1;
  const int l15 = lane & 15, l4 = lane >> 4;
  int aoff[2][2], boff[2][2];
#pragma unroll
  for (int m = 0; m < 2; m++)
#pragma unroll
    for (int s = 0; s < 2; s++) {
      int ra = wr * 32 + m * 16 + l15;
      int rb = wc * 32 + m * 16 + l15;
      int sl = s * 4 + l4;
      aoff[m][s] = ra * 64 + ((sl ^ (ra & 7)) * 8);
      boff[m][s] = rb * 64 + ((sl ^ (rb & 7)) * 8);
    }

  f32x4 zero = {0.f, 0.f, 0.f, 0.f};
  f32x4 acc[2][2];
  acc[0][0] = zero; acc[0][1] = zero; acc[1][0] = zero; acc[1][1] = zero;

  uint4 ax0, ax1;     // staged A (32B bf16)
  f32x4 bw[4];        // staged B (16 fp32)

  const int NT = K >> 6;

  auto g_load = [&](int kt) {
    const int kk = kt * 64;
    const ushort* ap = Xb + (size_t)(m0 + srow) * ldx + kk + sq * 16;
    ax0 = *(const uint4*)ap;
    ax1 = *(const uint4*)(ap + 8);
    const float* wp;
    if (kk < K1) wp = W1 + (size_t)(n0 + srow) * ldw1 + kk + sq * 16;
    else         wp = W2 + (size_t)(n0 + srow) * ldw2 + (kk - K1) + sq * 16;
    bw[0] = *(const f32x4*)wp;
    bw[1] = *(const f32x4*)(wp + 4);
    bw[2] = *(const f32x4*)(wp + 8);
    bw[3] = *(const f32x4*)(wp + 12);
  };
  auto s_write = [&](int buf) {
    *(uint4*)&lA[buf][wz0] = ax0;
    *(uint4*)&lA[buf][wz1] = ax1;
    uint4 b0, b1;
    b0.x = pk2bf(bw[0].x, bw[0].y); b0.y = pk2bf(bw[0].z, bw[0].w);
    b0.z = pk2bf(bw[1].x, bw[1].y); b0.w = pk2bf(bw[1].z, bw[1].w);
    b1.x = pk2bf(bw[2].x, bw[2].y); b1.y = pk2bf(bw[2].z, bw[2].w);
    b1.z = pk2bf(bw[3].x, bw[3].y); b1.w = pk2bf(bw[3].z, bw[3].w);
    *(uint4*)&lB[buf][wz0] = b0;
    *(uint4*)&lB[buf][wz1] = b1;
  };
  auto compute = [&](int buf) {
#pragma unroll
    for (int s = 0; s < 2; s++) {
      bf16x8 af0 = *(const bf16x8*)&lA[buf][aoff[0][s]];
      bf16x8 af1 = *(const bf16x8*)&lA[buf][aoff[1][s]];
      bf16x8 bf0 = *(const bf16x8*)&lB[buf][boff[0][s]];
      bf16x8 bf1 = *(const bf16x8*)&lB[buf][boff[1][s]];
      acc[0][0] = __builtin_amdgcn_mfma_f32_16x16x32_bf16(af0, bf0, acc[0][0], 0, 0, 0);
      acc[0][1] = __builtin_amdgcn_mfma_f32_16x16x32_bf16(af0, bf1, acc[0][1], 0, 0, 0);
      acc[1][0] = __builtin_amdgcn_mfma_f32_16x16x32_bf16(af1, bf0, acc[1][0], 0, 0, 0);
      acc[1][1] = __builtin_amdgcn_mfma_f32_16x16x32_bf16(af1, bf1, acc[1][1], 0, 0, 0);
    }
  };

  g_load(0);
  s_write(0);
  __syncthreads();
  int cur = 0;
  for (int kt = 0; kt < NT; kt++) {
    if (kt + 1 < NT) g_load(kt + 1);
    compute(cur);
    if (kt + 1 < NT) s_write(cur ^ 1);
    __syncthreads();
    cur ^= 1;
  }

#pragma unroll
  for (int m = 0; m < 2; m++)
#pragma unroll
    for (int n = 0; n < 2; n++) {
      const int col = n0 + wc * 32 + n * 16 + l15;
#pragma unroll
      for (int j = 0; j < 4; j++) {
        const int row = m0 + wr * 32 + m * 16 + l4 * 4 + j;
        C[(size_t)row * ldc + col] = acc[m][n][j];
      }
    }
}

// ---------------------------------------------------------------------------
// pack fp32 256x1024 -> bf16 with dst row stride 3072 (4 fused segments)
// ---------------------------------------------------------------------------
__global__ __launch_bounds__(256) void pack4(
    const float* __restrict__ s0, ushort* __restrict__ d0,
    const float* __restrict__ s1, ushort* __restrict__ d1,
    const float* __restrict__ s2, ushort* __restrict__ d2,
    const float* __restrict__ s3, ushort* __restrict__ d3)
{
  const int seg = blockIdx.x >> 8;
  const int row = blockIdx.x & 255;
  const int col = threadIdx.x * 4;
  const float* s = (seg == 0) ? s0 : (seg == 1) ? s1 : (seg == 2) ? s2 : s3;
  ushort* d = (seg == 0) ? d0 : (seg == 1) ? d1 : (seg == 2) ? d2 : d3;
  if (!s) return;
  float4 v = *(const float4*)(s + (size_t)row * 1024 + col);
  uint2 o;
  o.x = pk2bf(v.x, v.y);
  o.y = pk2bf(v.z, v.w);
  *(uint2*)(d + (size_t)row * 3072 + col) = o;
}

__global__ __launch_bounds__(256) void pack1(
    const float* __restrict__ s, ushort* __restrict__ d)
{
  const int row = blockIdx.x;
  const int col = threadIdx.x * 4;
  float4 v = *(const float4*)(s + (size_t)row * 1024 + col);
  uint2 o;
  o.x = pk2bf(v.x, v.y);
  o.y = pk2bf(v.z, v.w);
  *(uint2*)(d + (size_t)row * 3072 + col) = o;
}

// ---------------------------------------------------------------------------
// S[256,5120] + biases -> gates -> h,c ; optional bf16 h into packed X buffer
// ---------------------------------------------------------------------------
__global__ __launch_bounds__(256) void lstm_gates(
    const float* __restrict__ S,
    const float* __restrict__ bi, const float* __restrict__ bh,
    const float* __restrict__ c_prev,
    float* __restrict__ h_out, float* __restrict__ c_out,
    ushort* __restrict__ hb16,       // col 0 of next packed X (stride 3072)
    float* __restrict__ h_out2)
{
  int idx = blockIdx.x * 256 + threadIdx.x;
  int b = idx >> 10;
  int r = idx & 1023;
  const float* s = S + (size_t)b * (5 * R_);
  float s0 = s[r]        + bi[r]        + bh[r];
  float s1 = s[R_ + r]   + bi[R_ + r]   + bh[R_ + r];
  float s2 = s[2*R_ + r] + bi[2*R_ + r] + bh[2*R_ + r];
  float s3 = s[3*R_ + r] + bi[3*R_ + r] + bh[3*R_ + r];
  float s4 = s[4*R_ + r] + bi[4*R_ + r] + bh[4*R_ + r];
  float ig = 1.f / (1.f + __expf(-s0));
  float fg = 1.f / (1.f + __expf(-s1));
  float og = 1.f / (1.f + __expf(-s2));
  float it = fmaxf(s3, s4);
  float c  = fg * c_prev[idx] + ig * it;
  float h  = og * tanhf(c);
  h_out[idx] = h;
  c_out[idx] = c;
  if (hb16) hb16[(size_t)b * 3072 + r] = f2bf(h);
  if (h_out2) h_out2[idx] = h;
}

// ---------------------------------------------------------------------------
// attention scores: one wave per (b,l)
// ---------------------------------------------------------------------------
__global__ __launch_bounds__(256) void att_scores(
    float* __restrict__ scores,
    const float* __restrict__ p_att,
    const float* __restrict__ attH,
    const float* __restrict__ hb,
    const float* __restrict__ aw,
    const float* __restrict__ ab)
{
  int wid = blockIdx.x * 4 + (threadIdx.x >> 6);
  if (wid >= B_ * L_) return;
  int lane = threadIdx.x & 63;
  int b = wid / L_;
  int l = wid % L_;
  const float* p = p_att + ((size_t)b * L_ + l) * A_;
  const float* q = attH + (size_t)b * A_;
  float4 p0 = *(const float4*)(p + lane * 8);
  float4 p1 = *(const float4*)(p + lane * 8 + 4);
  float4 q0 = *(const float4*)(q + lane * 8);
  float4 q1 = *(const float4*)(q + lane * 8 + 4);
  float4 h0 = *(const float4*)(hb + lane * 8);
  float4 h1 = *(const float4*)(hb + lane * 8 + 4);
  float4 w0 = *(const float4*)(aw + lane * 8);
  float4 w1 = *(const float4*)(aw + lane * 8 + 4);
  float part = 0.f;
  part += tanhf(p0.x + q0.x + h0.x) * w0.x;
  part += tanhf(p0.y + q0.y + h0.y) * w0.y;
  part += tanhf(p0.z + q0.z + h0.z) * w0.z;
  part += tanhf(p0.w + q0.w + h0.w) * w0.w;
  part += tanhf(p1.x + q1.x + h1.x) * w1.x;
  part += tanhf(p1.y + q1.y + h1.y) * w1.y;
  part += tanhf(p1.z + q1.z + h1.z) * w1.z;
  part += tanhf(p1.w + q1.w + h1.w) * w1.w;
#pragma unroll
  for (int off = 32; off > 0; off >>= 1) part += __shfl_down(part, off);
  if (lane == 0) scores[wid] = part + ab[0];
}

__global__ __launch_bounds__(256) void att_softmax(float* __restrict__ sc)
{
  int b = blockIdx.x;
  int t = threadIdx.x;
  __shared__ float buf[256];
  float v = (t < L_) ? sc[b * L_ + t] : -1e30f;
  buf[t] = v;
  __syncthreads();
  for (int s = 128; s > 0; s >>= 1) {
    if (t < s) buf[t] = fmaxf(buf[t], buf[t + s]);
    __syncthreads();
  }
  float m = buf[0];
  __syncthreads();
  float e = (t < L_) ? __expf(v - m) : 0.f;
  buf[t] = e;
  __syncthreads();
  for (int s = 128; s > 0; s >>= 1) {
    if (t < s) buf[t] += buf[t + s];
    __syncthreads();
  }
  float inv = 1.f / buf[0];
  if (t < L_) sc[b * L_ + t] = e * inv;
}

// out(bf16, stride 3072)[b, d] = sum_l w[b,l] * feats[b,l,d]
__global__ __launch_bounds__(256) void att_weighted(
    ushort* __restrict__ outb,
    const float* __restrict__ w,
    const float* __restrict__ feats)
{
  int b = blockIdx.x >> 2;
  int dc = blockIdx.x & 3;
  int d = dc * 256 + threadIdx.x;
  const float* f = feats + (size_t)b * L_ * R_ + d;
  const float* wr = w + b * L_;
  float acc = 0.f;
  for (int l = 0; l < L_; l++) acc = fmaf(wr[l], f[(size_t)l * R_], acc);
  outb[(size_t)b * 3072 + d] = f2bf(acc);
}

// q2b(bf16) = q2f + h1 + emb2_b
__global__ __launch_bounds__(256) void make_q2(
    ushort* __restrict__ q2b, const float* __restrict__ q2f,
    const float* __restrict__ h1, const float* __restrict__ eb)
{
  int idx = blockIdx.x * 256 + threadIdx.x;
  q2b[idx] = f2bf(q2f[idx] + h1[idx] + eb[idx & (R_ - 1)]);
}

extern "C" void kernel_launch(void* const* d_in, const int* in_sizes, int n_in,
                              void* d_out, int out_size, void* d_ws, size_t ws_size,
                              hipStream_t stream)
{
  const float* xt        = (const float*)d_in[0];
  const float* fc        = (const float*)d_in[1];
  const float* att_feats = (const float*)d_in[2];
  const float* p_att     = (const float*)d_in[3];
  const float* st_h      = (const float*)d_in[4];
  const float* st_c      = (const float*)d_in[5];
  const float* wi[3] = {(const float*)d_in[6],  (const float*)d_in[10], (const float*)d_in[14]};
  const float* bi[3] = {(const float*)d_in[7],  (const float*)d_in[11], (const float*)d_in[15]};
  const float* wh[3] = {(const float*)d_in[8],  (const float*)d_in[12], (const float*)d_in[16]};
  const float* bh[3] = {(const float*)d_in[9],  (const float*)d_in[13], (const float*)d_in[17]};
  const float* a_hw[2] = {(const float*)d_in[18], (const float*)d_in[22]};
  const float* a_hb[2] = {(const float*)d_in[19], (const float*)d_in[23]};
  const float* a_aw[2] = {(const float*)d_in[20], (const float*)d_in[24]};
  const float* a_ab[2] = {(const float*)d_in[21], (const float*)d_in[25]};
  const float* emb2_w = (const float*)d_in[26];
  const float* emb2_b = (const float*)d_in[27];

  float* out    = (float*)d_out;
  float* out_h2 = out;                     // [256,1024]
  float* out_h  = out + 262144;            // [3,256,1024]
  float* out_c  = out + 262144 + 786432;   // [3,256,1024]
  const int BR = B_ * R_;

  // workspace (total 9,113,600 B — same footprint as round 1)
  float*  S    = (float*)d_ws;                   // 1,310,720 f = 5.24 MB
  ushort* Xb0  = (ushort*)(S + 1310720);         // 256x3072 bf16
  ushort* Xb1  = Xb0 + 786432;                   // 256x3072 bf16
  ushort* Xb2  = Xb0;                            // alias (Xb0 dead after gemm0)
  float*  attH = (float*)(Xb1 + 786432);         // 131072 f
  float*  sc   = attH + 131072;                  // 50176 f
  float*  q2f  = S;                              // alias (S dead after gates1)
  ushort* q2b  = (ushort*)(S + 262144);          // alias inside S

  dim3 blk(256);
  auto gemm = [&](float* C, int ldc, const ushort* Xb, int ldx,
                  const float* W1, int ldw1, int K1,
                  const float* W2, int ldw2, int K, int N) {
    dim3 grid(N / 64, 4);
    hipLaunchKernelGGL(gemm_mfma, grid, blk, 0, stream,
                       C, ldc, Xb, ldx, W1, ldw1, K1, W2, ldw2, K);
  };

  // pack xt, fc, st_h0 -> Xb0 ; st_h1 -> Xb1[:,2048:]
  pack4<<<1024, 256, 0, stream>>>(xt, Xb0, fc, Xb0 + 1024,
                                  st_h, Xb0 + 2048, st_h + BR, Xb1 + 2048);

  // ---- LSTM 0
  gemm(S, 5120, Xb0, 3072, wi[0], 2048, 2048, wh[0], 1024, 3072, 5120);
  pack1<<<256, 256, 0, stream>>>(st_h + 2 * BR, Xb2 + 2048);  // Xb0 dead now
  lstm_gates<<<1024, 256, 0, stream>>>(S, bi[0], bh[0], st_c,
                                       out_h, out_c, Xb1, nullptr);

  // ---- Attention 1 (query = h0 = Xb1[:, :1024])
  gemm(attH, 512, Xb1, 3072, a_hw[0], 1024, 1024, nullptr, 0, 1024, 512);
  att_scores<<<(B_ * L_) / 4, 256, 0, stream>>>(sc, p_att, attH, a_hb[0], a_aw[0], a_ab[0]);
  att_softmax<<<B_, 256, 0, stream>>>(sc);
  att_weighted<<<B_ * 4, 256, 0, stream>>>(Xb1 + 1024, sc, att_feats);

  // ---- LSTM 1 (X = [h0, ar1, st_h1] = Xb1)
  gemm(S, 5120, Xb1, 3072, wi[1], 2048, 2048, wh[1], 1024, 3072, 5120);
  lstm_gates<<<1024, 256, 0, stream>>>(S, bi[1], bh[1], st_c + BR,
                                       out_h + BR, out_c + BR, Xb2, nullptr);

  // ---- q2 = h1 + ar1 @ emb2_w^T + emb2_b  (ar1 = Xb1[:,1024:2048])
  gemm(q2f, 1024, Xb1 + 1024, 3072, emb2_w, 1024, 1024, nullptr, 0, 1024, 1024);
  make_q2<<<1024, 256, 0, stream>>>(q2b, q2f, out_h + BR, emb2_b);

  // ---- Attention 2 (query = q2b)
  gemm(attH, 512, q2b, 1024, a_hw[1], 1024, 1024, nullptr, 0, 1024, 512);
  att_scores<<<(B_ * L_) / 4, 256, 0, stream>>>(sc, p_att, attH, a_hb[1], a_aw[1], a_ab[1]);
  att_softmax<<<B_, 256, 0, stream>>>(sc);
  att_weighted<<<B_ * 4, 256, 0, stream>>>(Xb2 + 1024, sc, att_feats);

  // ---- LSTM 2 (X = [h1, ar2, st_h2] = Xb2)
  gemm(S, 5120, Xb2, 3072, wi[2], 2048, 2048, wh[2], 1024, 3072, 5120);
  lstm_gates<<<1024, 256, 0, stream>>>(S, bi[2], bh[2], st_c + 2 * BR,
                                       out_h + 2 * BR, out_c + 2 * BR,
                                       nullptr, out_h2);
}

// Round 3
// 320.400 us; speedup vs baseline: 9.5033x; 1.0790x over previous
//
#include <hip/hip_runtime.h>
#include <hip/hip_bf16.h>
#include <cmath>

// ---------------------------------------------------------------------------
// StackAttCore: 3x LSTM + 2x additive attention. B=256 L=196 R=1024 A=512 E=1024
// Round 3: split-K MFMA GEMMs (occupancy), fused softmax+weighted, fast tanh.
// ---------------------------------------------------------------------------

#define B_ 256
#define L_ 196
#define R_ 1024
#define A_ 512
#define E_ 1024

typedef __attribute__((ext_vector_type(8))) short bf16x8;
typedef __attribute__((ext_vector_type(4))) float f32x4;

__device__ inline ushort f2bf(float f) {
  __hip_bfloat16 h = __float2bfloat16(f);
  return *(ushort*)&h;
}
__device__ inline uint pk2bf(float lo, float hi) {
  float2 t; t.x = lo; t.y = hi;
  __hip_bfloat162 h = __float22bfloat162_rn(t);
  return *(uint*)&h;
}
__device__ inline float ftanh(float x) {
  float e = __expf(2.f * x);
  return 1.f - 2.f / (e + 1.f);
}

// ---------------------------------------------------------------------------
// Cpart[z][M,N] = Xb(bf16)[M, k0:k0+Ks] @ [W1|W2](fp32->bf16)[N, k0:k0+Ks]^T
// Tile 64x64, BK=64, 4 waves (2x2), 16x16x32 MFMA, XOR-swizzled LDS, dbuf.
// gridDim.z = nsplit; each z-slice writes its own partial C.
// ---------------------------------------------------------------------------
__global__ __launch_bounds__(256) void gemm_mfma(
    float* __restrict__ C, int ldc, size_t pstride,
    const ushort* __restrict__ Xb, int ldx,
    const float* __restrict__ W1, int ldw1, int K1,
    const float* __restrict__ W2, int ldw2,
    int K)
{
  __shared__ ushort lA[2][64 * 64];
  __shared__ ushort lB[2][64 * 64];
  const int tid = threadIdx.x;
  const int n0 = blockIdx.x * 64;
  const int m0 = blockIdx.y * 64;
  const int ns = gridDim.z;
  const int Ks = K / ns;
  const int k0 = blockIdx.z * Ks;
  C += (size_t)blockIdx.z * pstride;

  const int srow = tid >> 2;
  const int sq = tid & 3;
  const int wz0 = srow * 64 + (((sq * 2) ^ (srow & 7)) * 8);
  const int wz1 = srow * 64 + (((sq * 2 + 1) ^ (srow & 7)) * 8);

  const int lane = tid & 63;
  const int wid = tid >> 6;
  const int wr = wid >> 1, wc = wid & 1;
  const int l15 = lane & 15, l4 = lane >> 4;
  int aoff[2][2], boff[2][2];
#pragma unroll
  for (int m = 0; m < 2; m++)
#pragma unroll
    for (int s = 0; s < 2; s++) {
      int ra = wr * 32 + m * 16 + l15;
      int rb = wc * 32 + m * 16 + l15;
      int sl = s * 4 + l4;
      aoff[m][s] = ra * 64 + ((sl ^ (ra & 7)) * 8);
      boff[m][s] = rb * 64 + ((sl ^ (rb & 7)) * 8);
    }

  f32x4 zero = {0.f, 0.f, 0.f, 0.f};
  f32x4 acc[2][2];
  acc[0][0] = zero; acc[0][1] = zero; acc[1][0] = zero; acc[1][1] = zero;

  uint4 ax0, ax1;
  f32x4 bw[4];
  const int NT = Ks >> 6;

  auto g_load = [&](int kt) {
    const int kk = k0 + kt * 64;
    const ushort* ap = Xb + (size_t)(m0 + srow) * ldx + kk + sq * 16;
    ax0 = *(const uint4*)ap;
    ax1 = *(const uint4*)(ap + 8);
    const float* wp;
    if (kk < K1) wp = W1 + (size_t)(n0 + srow) * ldw1 + kk + sq * 16;
    else         wp = W2 + (size_t)(n0 + srow) * ldw2 + (kk - K1) + sq * 16;
    bw[0] = *(const f32x4*)wp;
    bw[1] = *(const f32x4*)(wp + 4);
    bw[2] = *(const f32x4*)(wp + 8);
    bw[3] = *(const f32x4*)(wp + 12);
  };
  auto s_write = [&](int buf) {
    *(uint4*)&lA[buf][wz0] = ax0;
    *(uint4*)&lA[buf][wz1] = ax1;
    uint4 b0, b1;
    b0.x = pk2bf(bw[0].x, bw[0].y); b0.y = pk2bf(bw[0].z, bw[0].w);
    b0.z = pk2bf(bw[1].x, bw[1].y); b0.w = pk2bf(bw[1].z, bw[1].w);
    b1.x = pk2bf(bw[2].x, bw[2].y); b1.y = pk2bf(bw[2].z, bw[2].w);
    b1.z = pk2bf(bw[3].x, bw[3].y); b1.w = pk2bf(bw[3].z, bw[3].w);
    *(uint4*)&lB[buf][wz0] = b0;
    *(uint4*)&lB[buf][wz1] = b1;
  };
  auto compute = [&](int buf) {
#pragma unroll
    for (int s = 0; s < 2; s++) {
      bf16x8 af0 = *(const bf16x8*)&lA[buf][aoff[0][s]];
      bf16x8 af1 = *(const bf16x8*)&lA[buf][aoff[1][s]];
      bf16x8 bf0 = *(const bf16x8*)&lB[buf][boff[0][s]];
      bf16x8 bf1 = *(const bf16x8*)&lB[buf][boff[1][s]];
      acc[0][0] = __builtin_amdgcn_mfma_f32_16x16x32_bf16(af0, bf0, acc[0][0], 0, 0, 0);
      acc[0][1] = __builtin_amdgcn_mfma_f32_16x16x32_bf16(af0, bf1, acc[0][1], 0, 0, 0);
      acc[1][0] = __builtin_amdgcn_mfma_f32_16x16x32_bf16(af1, bf0, acc[1][0], 0, 0, 0);
      acc[1][1] = __builtin_amdgcn_mfma_f32_16x16x32_bf16(af1, bf1, acc[1][1], 0, 0, 0);
    }
  };

  g_load(0);
  s_write(0);
  __syncthreads();
  int cur = 0;
  for (int kt = 0; kt < NT; kt++) {
    if (kt + 1 < NT) g_load(kt + 1);
    compute(cur);
    if (kt + 1 < NT) s_write(cur ^ 1);
    __syncthreads();
    cur ^= 1;
  }

#pragma unroll
  for (int m = 0; m < 2; m++)
#pragma unroll
    for (int n = 0; n < 2; n++) {
      const int col = n0 + wc * 32 + n * 16 + l15;
#pragma unroll
      for (int j = 0; j < 4; j++) {
        const int row = m0 + wr * 32 + m * 16 + l4 * 4 + j;
        C[(size_t)row * ldc + col] = acc[m][n][j];
      }
    }
}

// pack fp32 256x1024 -> bf16, dst row stride 3072 (4 segments)
__global__ __launch_bounds__(256) void pack4(
    const float* __restrict__ s0, ushort* __restrict__ d0,
    const float* __restrict__ s1, ushort* __restrict__ d1,
    const float* __restrict__ s2, ushort* __restrict__ d2,
    const float* __restrict__ s3, ushort* __restrict__ d3)
{
  const int seg = blockIdx.x >> 8;
  const int row = blockIdx.x & 255;
  const int col = threadIdx.x * 4;
  const float* s = (seg == 0) ? s0 : (seg == 1) ? s1 : (seg == 2) ? s2 : s3;
  ushort* d = (seg == 0) ? d0 : (seg == 1) ? d1 : (seg == 2) ? d2 : d3;
  if (!s) return;
  float4 v = *(const float4*)(s + (size_t)row * 1024 + col);
  uint2 o;
  o.x = pk2bf(v.x, v.y);
  o.y = pk2bf(v.z, v.w);
  *(uint2*)(d + (size_t)row * 3072 + col) = o;
}

__global__ __launch_bounds__(256) void pack1(
    const float* __restrict__ s, ushort* __restrict__ d)
{
  const int row = blockIdx.x;
  const int col = threadIdx.x * 4;
  float4 v = *(const float4*)(s + (size_t)row * 1024 + col);
  uint2 o;
  o.x = pk2bf(v.x, v.y);
  o.y = pk2bf(v.z, v.w);
  *(uint2*)(d + (size_t)row * 3072 + col) = o;
}

// ---------------------------------------------------------------------------
// gates: sum ns partials of S, add biases, sigmoid/max/tanh -> h, c (float4)
// ---------------------------------------------------------------------------
__global__ __launch_bounds__(256) void lstm_gates(
    const float* __restrict__ Sp, int ns,
    const float* __restrict__ bi, const float* __restrict__ bh,
    const float* __restrict__ c_prev,
    float* __restrict__ h_out, float* __restrict__ c_out,
    ushort* __restrict__ hb16,
    float* __restrict__ h_out2)
{
  const int idx = blockIdx.x * 256 + threadIdx.x;   // 0..65535
  const int b = idx >> 8;
  const int c4 = (idx & 255) * 4;
  const size_t base = (size_t)b * 5120 + c4;

  f32x4 g[5];
#pragma unroll
  for (int j = 0; j < 5; j++) g[j] = (f32x4){0.f, 0.f, 0.f, 0.f};
  for (int s = 0; s < ns; s++) {
    const float* sp = Sp + (size_t)s * 1310720 + base;
#pragma unroll
    for (int j = 0; j < 5; j++) g[j] += *(const f32x4*)(sp + j * 1024);
  }
#pragma unroll
  for (int j = 0; j < 5; j++) {
    g[j] += *(const f32x4*)(bi + j * 1024 + c4);
    g[j] += *(const f32x4*)(bh + j * 1024 + c4);
  }

  const int oidx = b * 1024 + c4;
  f32x4 cp = *(const f32x4*)(c_prev + oidx);
  f32x4 hv, cv;
#pragma unroll
  for (int i = 0; i < 4; i++) {
    float ig = 1.f / (1.f + __expf(-g[0][i]));
    float fg = 1.f / (1.f + __expf(-g[1][i]));
    float og = 1.f / (1.f + __expf(-g[2][i]));
    float it = fmaxf(g[3][i], g[4][i]);
    float c  = fg * cp[i] + ig * it;
    cv[i] = c;
    hv[i] = og * ftanh(c);
  }
  *(f32x4*)(h_out + oidx) = hv;
  *(f32x4*)(c_out + oidx) = cv;
  if (hb16) {
    uint2 o;
    o.x = pk2bf(hv[0], hv[1]);
    o.y = pk2bf(hv[2], hv[3]);
    *(uint2*)(hb16 + (size_t)b * 3072 + c4) = o;
  }
  if (h_out2) *(f32x4*)(h_out2 + oidx) = hv;
}

// ---------------------------------------------------------------------------
// scores[b,l] = sum_a tanh(p + sum_s attHp[s] + hb) * aw + ab ; wave per (b,l)
// ---------------------------------------------------------------------------
__global__ __launch_bounds__(256) void att_scores(
    float* __restrict__ scores,
    const float* __restrict__ p_att,
    const float* __restrict__ attHp, int ns,
    const float* __restrict__ hb,
    const float* __restrict__ aw,
    const float* __restrict__ ab)
{
  int wid = blockIdx.x * 4 + (threadIdx.x >> 6);
  if (wid >= B_ * L_) return;
  int lane = threadIdx.x & 63;
  int b = wid / L_;
  int l = wid % L_;
  const float* p = p_att + ((size_t)b * L_ + l) * A_;

  f32x4 q0 = {0.f, 0.f, 0.f, 0.f}, q1 = q0;
  for (int s = 0; s < ns; s++) {
    const float* qp = attHp + (size_t)s * 131072 + (size_t)b * A_ + lane * 8;
    q0 += *(const f32x4*)qp;
    q1 += *(const f32x4*)(qp + 4);
  }
  f32x4 p0 = *(const f32x4*)(p + lane * 8);
  f32x4 p1 = *(const f32x4*)(p + lane * 8 + 4);
  f32x4 h0 = *(const f32x4*)(hb + lane * 8);
  f32x4 h1 = *(const f32x4*)(hb + lane * 8 + 4);
  f32x4 w0 = *(const f32x4*)(aw + lane * 8);
  f32x4 w1 = *(const f32x4*)(aw + lane * 8 + 4);
  float part = 0.f;
#pragma unroll
  for (int i = 0; i < 4; i++) part += ftanh(p0[i] + q0[i] + h0[i]) * w0[i];
#pragma unroll
  for (int i = 0; i < 4; i++) part += ftanh(p1[i] + q1[i] + h1[i]) * w1[i];
#pragma unroll
  for (int off = 32; off > 0; off >>= 1) part += __shfl_down(part, off);
  if (lane == 0) scores[wid] = part + ab[0];
}

// ---------------------------------------------------------------------------
// fused softmax(196) + weighted sum over att_feats -> bf16 (stride 3072)
// block = (b, 256-col chunk)
// ---------------------------------------------------------------------------
__global__ __launch_bounds__(256) void att_smw(
    ushort* __restrict__ dst,
    const float* __restrict__ sc,
    const float* __restrict__ feats)
{
  const int b = blockIdx.x >> 2;
  const int dc = blockIdx.x & 3;
  const int t = threadIdx.x;
  __shared__ float red[256];
  __shared__ float wbuf[256];

  float v = (t < L_) ? sc[b * L_ + t] : -1e30f;
  red[t] = v;
  __syncthreads();
  for (int s = 128; s > 0; s >>= 1) {
    if (t < s) red[t] = fmaxf(red[t], red[t + s]);
    __syncthreads();
  }
  float m = red[0];
  __syncthreads();
  float e = (t < L_) ? __expf(v - m) : 0.f;
  red[t] = e;
  __syncthreads();
  for (int s = 128; s > 0; s >>= 1) {
    if (t < s) red[t] += red[t + s];
    __syncthreads();
  }
  wbuf[t] = e * (1.f / red[0]);
  __syncthreads();

  const int d = dc * 256 + t;
  const float* f = feats + (size_t)b * L_ * R_ + d;
  float acc = 0.f;
#pragma unroll 4
  for (int l = 0; l < L_; l++) acc = fmaf(wbuf[l], f[(size_t)l * R_], acc);
  dst[(size_t)b * 3072 + d] = f2bf(acc);
}

// q2b(bf16,[256,1024]) = sum_s q2p[s] + h1 + emb2_b
__global__ __launch_bounds__(256) void make_q2(
    ushort* __restrict__ q2b, const float* __restrict__ q2p, int ns,
    const float* __restrict__ h1, const float* __restrict__ eb)
{
  const int idx = blockIdx.x * 256 + threadIdx.x;   // 0..65535
  const int b = idx >> 8;
  const int c4 = (idx & 255) * 4;
  const int oidx = b * 1024 + c4;
  f32x4 a = {0.f, 0.f, 0.f, 0.f};
  for (int s = 0; s < ns; s++)
    a += *(const f32x4*)(q2p + (size_t)s * 262144 + oidx);
  a += *(const f32x4*)(h1 + oidx);
  a += *(const f32x4*)(eb + c4);
  uint2 o;
  o.x = pk2bf(a[0], a[1]);
  o.y = pk2bf(a[2], a[3]);
  *(uint2*)(q2b + oidx) = o;
}

extern "C" void kernel_launch(void* const* d_in, const int* in_sizes, int n_in,
                              void* d_out, int out_size, void* d_ws, size_t ws_size,
                              hipStream_t stream)
{
  const float* xt        = (const float*)d_in[0];
  const float* fc        = (const float*)d_in[1];
  const float* att_feats = (const float*)d_in[2];
  const float* p_att     = (const float*)d_in[3];
  const float* st_h      = (const float*)d_in[4];
  const float* st_c      = (const float*)d_in[5];
  const float* wi[3] = {(const float*)d_in[6],  (const float*)d_in[10], (const float*)d_in[14]};
  const float* bi[3] = {(const float*)d_in[7],  (const float*)d_in[11], (const float*)d_in[15]};
  const float* wh[3] = {(const float*)d_in[8],  (const float*)d_in[12], (const float*)d_in[16]};
  const float* bh[3] = {(const float*)d_in[9],  (const float*)d_in[13], (const float*)d_in[17]};
  const float* a_hw[2] = {(const float*)d_in[18], (const float*)d_in[22]};
  const float* a_hb[2] = {(const float*)d_in[19], (const float*)d_in[23]};
  const float* a_aw[2] = {(const float*)d_in[20], (const float*)d_in[24]};
  const float* a_ab[2] = {(const float*)d_in[21], (const float*)d_in[25]};
  const float* emb2_w = (const float*)d_in[26];
  const float* emb2_b = (const float*)d_in[27];

  float* out    = (float*)d_out;
  float* out_h2 = out;
  float* out_h  = out + 262144;
  float* out_c  = out + 262144 + 786432;
  const int BR = B_ * R_;

  // split-K factor chosen by available workspace
  // bytes(ns) = ns*5767168 + 3346432
  int ns = (ws_size >= 4u * 5767168u + 3346432u) ? 4
         : (ws_size >= 2u * 5767168u + 3346432u) ? 2 : 1;

  float*  Sp   = (float*)d_ws;                     // ns * 1310720 f
  ushort* Xb0  = (ushort*)(Sp + (size_t)ns * 1310720);
  ushort* Xb1  = Xb0 + 786432;
  ushort* Xb2  = Xb0;                              // alias (Xb0 rows dead after gemm0)
  float*  attHp = (float*)(Xb1 + 786432);          // ns * 131072 f
  float*  sc   = attHp + (size_t)ns * 131072;      // 50176 f
  float*  q2p  = Sp;                               // alias (Sp dead)
  ushort* q2b  = (ushort*)(Sp + (size_t)ns * 262144);

  dim3 blk(256);
  auto gemm = [&](float* C, int ldc, const ushort* Xb, int ldx,
                  const float* W1, int ldw1, int K1,
                  const float* W2, int ldw2, int K, int N) {
    dim3 grid(N / 64, 4, ns);
    hipLaunchKernelGGL(gemm_mfma, grid, blk, 0, stream,
                       C, ldc, (size_t)256 * ldc, Xb, ldx, W1, ldw1, K1, W2, ldw2, K);
  };

  // pack xt, fc, st_h0 -> Xb0 ; st_h1 -> Xb1[:,2048:]
  pack4<<<1024, 256, 0, stream>>>(xt, Xb0, fc, Xb0 + 1024,
                                  st_h, Xb0 + 2048, st_h + BR, Xb1 + 2048);

  // ---- LSTM 0
  gemm(Sp, 5120, Xb0, 3072, wi[0], 2048, 2048, wh[0], 1024, 3072, 5120);
  pack1<<<256, 256, 0, stream>>>(st_h + 2 * BR, Xb2 + 2048);
  lstm_gates<<<256, 256, 0, stream>>>(Sp, ns, bi[0], bh[0], st_c,
                                      out_h, out_c, Xb1, nullptr);

  // ---- Attention 1 (query = h0 = Xb1[:, :1024])
  gemm(attHp, 512, Xb1, 3072, a_hw[0], 1024, 1024, nullptr, 0, 1024, 512);
  att_scores<<<(B_ * L_) / 4, 256, 0, stream>>>(sc, p_att, attHp, ns,
                                                a_hb[0], a_aw[0], a_ab[0]);
  att_smw<<<B_ * 4, 256, 0, stream>>>(Xb1 + 1024, sc, att_feats);

  // ---- LSTM 1 (X = [h0, ar1, st_h1] = Xb1)
  gemm(Sp, 5120, Xb1, 3072, wi[1], 2048, 2048, wh[1], 1024, 3072, 5120);
  lstm_gates<<<256, 256, 0, stream>>>(Sp, ns, bi[1], bh[1], st_c + BR,
                                      out_h + BR, out_c + BR, Xb2, nullptr);

  // ---- q2 = h1 + ar1 @ emb2_w^T + emb2_b
  gemm(q2p, 1024, Xb1 + 1024, 3072, emb2_w, 1024, 1024, nullptr, 0, 1024, 1024);
  make_q2<<<256, 256, 0, stream>>>(q2b, q2p, ns, out_h + BR, emb2_b);

  // ---- Attention 2 (query = q2b)
  gemm(attHp, 512, q2b, 1024, a_hw[1], 1024, 1024, nullptr, 0, 1024, 512);
  att_scores<<<(B_ * L_) / 4, 256, 0, stream>>>(sc, p_att, attHp, ns,
                                                a_hb[1], a_aw[1], a_ab[1]);
  att_smw<<<B_ * 4, 256, 0, stream>>>(Xb2 + 1024, sc, att_feats);

  // ---- LSTM 2 (X = [h1, ar2, st_h2] = Xb2)
  gemm(Sp, 5120, Xb2, 3072, wi[2], 2048, 2048, wh[2], 1024, 3072, 5120);
  lstm_gates<<<256, 256, 0, stream>>>(Sp, ns, bi[2], bh[2], st_c + 2 * BR,
                                      out_h + 2 * BR, out_c + 2 * BR,
                                      nullptr, out_h2);
}